// Round 1
// baseline (5966.994 us; speedup 1.0000x reference)
//
#include <hip/hip_runtime.h>
#include <hip/hip_bf16.h>

// Softsplat forward (summation splatting).
// B=4, C=64, H=512, W=512, fp32.
// One thread per source pixel: compute 4 bilinear taps once, reuse across all
// 64 channels. 4 atomicAdds per (pixel, channel).

#define B_ 4
#define C_ 64
#define H_ 512
#define W_ 512
#define HW_ (H_ * W_)

__global__ __launch_bounds__(256) void softsplat_fwd(
    const float* __restrict__ image,   // [B, C, H, W]
    const float* __restrict__ flow,    // [B, 2, H, W]
    float* __restrict__ out)           // [B, C, H, W], pre-zeroed
{
    int p = blockIdx.x * blockDim.x + threadIdx.x;   // 0 .. B*HW-1
    int b  = p >> 18;              // HW = 2^18
    int yx = p & (HW_ - 1);
    int y  = yx >> 9;              // W = 2^9
    int x  = yx & (W_ - 1);

    float fx = flow[(size_t)b * 2 * HW_ + yx] + (float)x;
    float fy = flow[(size_t)b * 2 * HW_ + HW_ + yx] + (float)y;

    float x0f = floorf(fx);
    float y0f = floorf(fy);
    int x0 = (int)x0f;
    int y0 = (int)y0f;
    float wx1 = fx - x0f, wx0 = 1.0f - wx1;
    float wy1 = fy - y0f, wy0 = 1.0f - wy1;

    // 4 taps: (y0,x0) (y0,x1) (y1,x0) (y1,x1)
    int   toff[4];
    float tw[4];
    int   nt = 0;

    int x1 = x0 + 1, y1 = y0 + 1;
    bool vx0 = (x0 >= 0) & (x0 < W_);
    bool vx1 = (x1 >= 0) & (x1 < W_);
    bool vy0 = (y0 >= 0) & (y0 < H_);
    bool vy1 = (y1 >= 0) & (y1 < H_);

    if (vy0 & vx0) { toff[nt] = y0 * W_ + x0; tw[nt] = wx0 * wy0; nt++; }
    if (vy0 & vx1) { toff[nt] = y0 * W_ + x1; tw[nt] = wx1 * wy0; nt++; }
    if (vy1 & vx0) { toff[nt] = y1 * W_ + x0; tw[nt] = wx0 * wy1; nt++; }
    if (vy1 & vx1) { toff[nt] = y1 * W_ + x1; tw[nt] = wx1 * wy1; nt++; }

    const float* img_b = image + (size_t)b * C_ * HW_ + yx;
    float*       out_b = out   + (size_t)b * C_ * HW_;

    for (int c = 0; c < C_; ++c) {
        float val = img_b[(size_t)c * HW_];            // coalesced across lanes
        float* oc = out_b + (size_t)c * HW_;
        #pragma unroll 4
        for (int t = 0; t < 4; ++t) {
            if (t < nt) atomicAdd(oc + toff[t], val * tw[t]);
        }
    }
}

extern "C" void kernel_launch(void* const* d_in, const int* in_sizes, int n_in,
                              void* d_out, int out_size, void* d_ws, size_t ws_size,
                              hipStream_t stream) {
    const float* image = (const float*)d_in[0];
    const float* flow  = (const float*)d_in[1];
    float* out = (float*)d_out;

    // d_out is poisoned with 0xAA before every call — zero it on-stream.
    hipMemsetAsync(out, 0, (size_t)out_size * sizeof(float), stream);

    int pixels = B_ * HW_;                 // 1,048,576
    int block = 256;
    int grid = pixels / block;             // 4096
    softsplat_fwd<<<grid, block, 0, stream>>>(image, flow, out);
}